// Round 8
// baseline (18.632 us; speedup 1.0000x reference)
//
#include <hip/hip_runtime.h>

#define B_    8
#define N_    128
#define NB_   32
#define NORB_ 128
#define RPB   8      // rows per block
#define OPB   16     // orbitals per block
#define THREADS 512
#define RPAD  18     // red row stride (16 used + 2 pad)

__global__ __launch_bounds__(THREADS, 4) void bobf_kernel(
    const float* __restrict__ chi,
    const float* __restrict__ W,
    float* __restrict__ out)
{
    __shared__ float Sp[16][NB_];                      // 2 KB
    __shared__ float S[NB_];
    __shared__ __align__(16) float red[32][RPB][RPAD]; // 18.4 KB

    const int t   = threadIdx.x;
    const int blk = blockIdx.x;
    const int b    = blk >> 7;            // 0..7
    const int rowg = (blk >> 3) & 15;     // 0..15
    const int og   = blk & 7;             // 0..7
    const int i0   = rowg * RPB;
    const int o0   = og * OPB;

    // ---- Stage 1: S[k] = sum_j chi[b,j,k] (coalesced 128B rows) ----
    {
        const int k = t & 31;
        const int g = t >> 5;                          // 0..15, 8 rows each
        const float* base = chi + (b * N_) * NB_ + k;
        float s = 0.f;
        #pragma unroll
        for (int jj = 0; jj < 8; ++jj) s += base[(g * 8 + jj) * NB_];
        Sp[g][k] = s;
    }
    __syncthreads();
    if (t < NB_) {
        float s = 0.f;
        #pragma unroll
        for (int g = 0; g < 16; ++g) s += Sp[g][t];
        S[t] = s;
    }

    // ---- Thread tile: q-chunk, 2 rows, 4 orbitals ----
    const int q  = t >> 4;               // 0..31  (k == q within chunk)
    const int r0 = ((t >> 2) & 3) * 2;   // 0,2,4,6
    const int oq = t & 3;                // 0..3

    // x rows into registers (compile-time indexed only; full unroll below)
    const float* row0 = chi + (b * N_ + i0 + r0) * NB_;
    const float* row1 = row0 + NB_;
    float x0s[32], x1s[32];
    #pragma unroll
    for (int u = 0; u < 8; ++u) {
        const float4 v0 = ((const float4*)row0)[u];
        const float4 v1 = ((const float4*)row1)[u];
        x0s[u * 4 + 0] = v0.x; x0s[u * 4 + 1] = v0.y; x0s[u * 4 + 2] = v0.z; x0s[u * 4 + 3] = v0.w;
        x1s[u * 4 + 0] = v1.x; x1s[u * 4 + 1] = v1.y; x1s[u * 4 + 2] = v1.z; x1s[u * 4 + 3] = v1.w;
    }

    __syncthreads();                     // S ready
    const float inv = 1.0f / (float)(N_ - 1);
    const float y0 = (S[q] - row0[q]) * inv;   // scalar re-load, L1/L2-hot
    const float y1 = (S[q] - row1[q]) * inv;

    // ---- Main: 32 iters, fully unrolled; W dwordx4 is the only memory op ----
    const float* Wp = W + (q * 32) * NORB_ + o0 + oq * 4;
    float4 a0 = {0,0,0,0}, a1 = {0,0,0,0};
    #pragma unroll
    for (int j = 0; j < 32; ++j) {
        const float4 wv = *(const float4*)(Wp + j * NORB_);
        const float p0 = y0 * x0s[j];
        const float p1 = y1 * x1s[j];
        a0.x += p0 * wv.x; a0.y += p0 * wv.y; a0.z += p0 * wv.z; a0.w += p0 * wv.w;
        a1.x += p1 * wv.x; a1.y += p1 * wv.y; a1.z += p1 * wv.z; a1.w += p1 * wv.w;
    }

    // ---- Epilogue: partials -> LDS -> 32-way q-reduce ----
    {
        float* rq = &red[q][r0][oq * 4];
        *(float4*)rq = a0;
        *(float4*)(rq + RPAD) = a1;
    }
    __syncthreads();
    if (t < RPB * OPB) {                 // 128 outputs
        const int r = t >> 4, o = t & 15;
        float v = 0.f;
        #pragma unroll
        for (int qq = 0; qq < 32; ++qq) v += red[qq][r][o];
        out[(b * N_ + i0 + r) * NORB_ + o0 + o] = v;
    }
}

extern "C" void kernel_launch(void* const* d_in, const int* in_sizes, int n_in,
                              void* d_out, int out_size, void* d_ws, size_t ws_size,
                              hipStream_t stream) {
    const float* chi = (const float*)d_in[0];
    const float* W   = (const float*)d_in[1];
    float* out = (float*)d_out;
    dim3 grid(1024);                     // 8 b x 16 rowg x 8 og
    dim3 block(THREADS);
    hipLaunchKernelGGL(bobf_kernel, grid, block, 0, stream, chi, W, out);
}

// Round 9
// 15.199 us; speedup vs baseline: 1.2259x; 1.2259x over previous
//
#include <hip/hip_runtime.h>

#define B_    8
#define N_    128
#define NB_   32
#define NORB_ 128
#define RPB   8      // rows per block
#define OPB   16     // orbitals per block
#define THREADS 512
#define RPAD  18     // red row stride (16 used + 2 pad)

__global__ __launch_bounds__(THREADS, 8) void bobf_kernel(
    const float* __restrict__ chi,
    const float* __restrict__ W,
    float* __restrict__ out)
{
    __shared__ float Sp[16][NB_];                      // 2 KB
    __shared__ float S[NB_];
    __shared__ __align__(16) float xT[NB_][RPB];       // xT[l][r], 1 KB
    __shared__ __align__(16) float red[32][RPB][RPAD]; // 18.4 KB

    const int t   = threadIdx.x;
    const int blk = blockIdx.x;
    const int b    = blk >> 7;            // 0..7
    const int rowg = (blk >> 3) & 15;     // 0..15
    const int og   = blk & 7;             // 0..7
    const int i0   = rowg * RPB;
    const int o0   = og * OPB;

    // ---- Stage 1: S[k] partials (coalesced) + xT build ----
    {
        const int k = t & 31;
        const int g = t >> 5;                          // 0..15, 8 rows each
        const float* base = chi + (b * N_) * NB_ + k;
        float s = 0.f;
        #pragma unroll
        for (int jj = 0; jj < 8; ++jj) s += base[(g * 8 + jj) * NB_];
        Sp[g][k] = s;
    }
    if (t < RPB * NB_) {                               // 256 threads
        const int r = t >> 5, l = t & 31;
        xT[l][r] = chi[(b * N_ + i0 + r) * NB_ + l];
    }
    __syncthreads();
    if (t < NB_) {
        float s = 0.f;
        #pragma unroll
        for (int g = 0; g < 16; ++g) s += Sp[g][t];
        S[t] = s;
    }
    __syncthreads();

    // ---- Main: thread = (q, rg, oq); 2 rows x 4 orbitals ----
    const int q  = t >> 4;               // 0..31  (k == q within chunk)
    const int rg = (t >> 2) & 3;         // 0..3
    const int oq = t & 3;                // 0..3
    const int r0 = rg * 2;

    const float inv = 1.0f / (float)(N_ - 1);
    const float Sq = S[q];
    const float y0 = (Sq - xT[q][r0 + 0]) * inv;
    const float y1 = (Sq - xT[q][r0 + 1]) * inv;

    const float4* Wf  = (const float4*)(W + (q * 32) * NORB_ + o0 + oq * 4);
    const float*  xjp = &xT[0][r0];

    float4 a0 = {0,0,0,0}, a1 = {0,0,0,0};
    #pragma unroll 8
    for (int j = 0; j < 32; ++j) {
        const float2 xv = *(const float2*)(xjp + j * RPB);  // xT[j][r0..r0+1] broadcast
        const float4 wv = Wf[j * (NORB_ / 4)];              // W[q*32+j][o..o+3]
        const float p0 = y0 * xv.x;
        const float p1 = y1 * xv.y;
        a0.x += p0 * wv.x; a0.y += p0 * wv.y; a0.z += p0 * wv.z; a0.w += p0 * wv.w;
        a1.x += p1 * wv.x; a1.y += p1 * wv.y; a1.z += p1 * wv.z; a1.w += p1 * wv.w;
    }

    // ---- Epilogue: partials -> LDS -> 32-way q-reduce ----
    {
        float* rq = &red[q][0][0] + oq * 4;
        *(float4*)&rq[(r0 + 0) * RPAD] = a0;
        *(float4*)&rq[(r0 + 1) * RPAD] = a1;
    }
    __syncthreads();
    if (t < RPB * OPB) {                 // 128 outputs
        const int r = t >> 4, o = t & 15;
        float v = 0.f;
        #pragma unroll
        for (int qq = 0; qq < 32; ++qq) v += red[qq][r][o];
        out[(b * N_ + i0 + r) * NORB_ + o0 + o] = v;
    }
}

extern "C" void kernel_launch(void* const* d_in, const int* in_sizes, int n_in,
                              void* d_out, int out_size, void* d_ws, size_t ws_size,
                              hipStream_t stream) {
    const float* chi = (const float*)d_in[0];
    const float* W   = (const float*)d_in[1];
    float* out = (float*)d_out;
    dim3 grid(1024);                     // 8 b x 16 rowg x 8 og
    dim3 block(THREADS);
    hipLaunchKernelGGL(bobf_kernel, grid, block, 0, stream, chi, W, out);
}

// Round 10
// 11.542 us; speedup vs baseline: 1.6143x; 1.3169x over previous
//
#include <hip/hip_runtime.h>

#define B_    8
#define N_    128
#define NB_   32
#define NORB_ 128
#define RPB   32     // rows per block
#define OPB   16     // orbitals per block
#define THREADS 512
#define RPAD  20     // red row stride (16 used + 4 pad, float4-aligned)

__global__ __launch_bounds__(THREADS, 2) void bobf_kernel(
    const float* __restrict__ chi,
    const float* __restrict__ W,
    float* __restrict__ out)
{
    __shared__ float Sp[16][NB_];                      // 2 KB
    __shared__ float S[NB_];
    __shared__ __align__(16) float xT[NB_][RPB];       // xT[l][r], 4 KB
    __shared__ __align__(16) float red[32][RPB][RPAD]; // 80 KB

    const int t   = threadIdx.x;
    const int blk = blockIdx.x;
    const int b    = blk >> 5;            // 0..7
    const int rowg = (blk >> 3) & 3;      // 0..3
    const int og   = blk & 7;             // 0..7
    const int i0   = rowg * RPB;
    const int o0   = og * OPB;

    // ---- Stage 1: S[k] partials (coalesced) + xT build (32 rows) ----
    {
        const int k = t & 31;
        const int g = t >> 5;                          // 0..15, 8 rows each
        const float* base = chi + (b * N_) * NB_ + k;
        float s = 0.f;
        #pragma unroll
        for (int jj = 0; jj < 8; ++jj) s += base[(g * 8 + jj) * NB_];
        Sp[g][k] = s;
    }
    #pragma unroll
    for (int e = 0; e < 2; ++e) {                      // 1024 xT entries, 512 thr
        const int idx = t + e * THREADS;
        const int r = idx >> 5, l = idx & 31;
        xT[l][r] = chi[(b * N_ + i0 + r) * NB_ + l];
    }
    __syncthreads();
    if (t < NB_) {
        float s = 0.f;
        #pragma unroll
        for (int g = 0; g < 16; ++g) s += Sp[g][t];
        S[t] = s;
    }
    __syncthreads();

    // ---- Main: thread = (q, rg, oq); 8 rows x 4 orbitals ----
    const int q  = t >> 4;               // 0..31  (k == q within chunk)
    const int rg = (t >> 2) & 3;         // 0..3
    const int oq = t & 3;                // 0..3
    const int r0 = rg * 8;

    const float inv = 1.0f / (float)(N_ - 1);
    const float Sq = S[q];
    float y[8];
    {
        const float4 xa = *(const float4*)&xT[q][r0];
        const float4 xb = *(const float4*)&xT[q][r0 + 4];
        y[0] = (Sq - xa.x) * inv; y[1] = (Sq - xa.y) * inv;
        y[2] = (Sq - xa.z) * inv; y[3] = (Sq - xa.w) * inv;
        y[4] = (Sq - xb.x) * inv; y[5] = (Sq - xb.y) * inv;
        y[6] = (Sq - xb.z) * inv; y[7] = (Sq - xb.w) * inv;
    }

    const float4* Wf  = (const float4*)(W + (q * 32) * NORB_ + o0 + oq * 4);
    const float*  xjp = &xT[0][r0];

    float4 a0 = {0,0,0,0}, a1 = {0,0,0,0}, a2 = {0,0,0,0}, a3 = {0,0,0,0};
    float4 a4 = {0,0,0,0}, a5 = {0,0,0,0}, a6 = {0,0,0,0}, a7 = {0,0,0,0};
    #pragma unroll 8
    for (int j = 0; j < 32; ++j) {
        const float4 xva = *(const float4*)(xjp + j * RPB);      // xT[j][r0..r0+3]
        const float4 xvb = *(const float4*)(xjp + j * RPB + 4);  // xT[j][r0+4..r0+7]
        const float4 wv  = Wf[j * (NORB_ / 4)];                  // W[q*32+j][o..o+3]
        const float p0 = y[0] * xva.x;
        const float p1 = y[1] * xva.y;
        const float p2 = y[2] * xva.z;
        const float p3 = y[3] * xva.w;
        const float p4 = y[4] * xvb.x;
        const float p5 = y[5] * xvb.y;
        const float p6 = y[6] * xvb.z;
        const float p7 = y[7] * xvb.w;
        a0.x += p0 * wv.x; a0.y += p0 * wv.y; a0.z += p0 * wv.z; a0.w += p0 * wv.w;
        a1.x += p1 * wv.x; a1.y += p1 * wv.y; a1.z += p1 * wv.z; a1.w += p1 * wv.w;
        a2.x += p2 * wv.x; a2.y += p2 * wv.y; a2.z += p2 * wv.z; a2.w += p2 * wv.w;
        a3.x += p3 * wv.x; a3.y += p3 * wv.y; a3.z += p3 * wv.z; a3.w += p3 * wv.w;
        a4.x += p4 * wv.x; a4.y += p4 * wv.y; a4.z += p4 * wv.z; a4.w += p4 * wv.w;
        a5.x += p5 * wv.x; a5.y += p5 * wv.y; a5.z += p5 * wv.z; a5.w += p5 * wv.w;
        a6.x += p6 * wv.x; a6.y += p6 * wv.y; a6.z += p6 * wv.z; a6.w += p6 * wv.w;
        a7.x += p7 * wv.x; a7.y += p7 * wv.y; a7.z += p7 * wv.z; a7.w += p7 * wv.w;
    }

    // ---- Epilogue: partials -> LDS -> 32-way q-reduce ----
    {
        float* rq = &red[q][0][0] + oq * 4;
        *(float4*)&rq[(r0 + 0) * RPAD] = a0;
        *(float4*)&rq[(r0 + 1) * RPAD] = a1;
        *(float4*)&rq[(r0 + 2) * RPAD] = a2;
        *(float4*)&rq[(r0 + 3) * RPAD] = a3;
        *(float4*)&rq[(r0 + 4) * RPAD] = a4;
        *(float4*)&rq[(r0 + 5) * RPAD] = a5;
        *(float4*)&rq[(r0 + 6) * RPAD] = a6;
        *(float4*)&rq[(r0 + 7) * RPAD] = a7;
    }
    __syncthreads();
    {
        const int r = t >> 4, o = t & 15;              // 512 outputs
        float v = 0.f;
        #pragma unroll
        for (int qq = 0; qq < 32; ++qq) v += red[qq][r][o];
        out[(b * N_ + i0 + r) * NORB_ + o0 + o] = v;
    }
}

extern "C" void kernel_launch(void* const* d_in, const int* in_sizes, int n_in,
                              void* d_out, int out_size, void* d_ws, size_t ws_size,
                              hipStream_t stream) {
    const float* chi = (const float*)d_in[0];
    const float* W   = (const float*)d_in[1];
    float* out = (float*)d_out;
    dim3 grid(B_ * (N_ / RPB) * (NORB_ / OPB));   // 8*4*8 = 256 blocks
    dim3 block(THREADS);
    hipLaunchKernelGGL(bobf_kernel, grid, block, 0, stream, chi, W, out);
}